// Round 8
// baseline (512.312 us; speedup 1.0000x reference)
//
#include <hip/hip_runtime.h>
#include <math.h>

// Problem dims (fixed by reference)
#define B_   4
#define L_   1024
#define D_   512
#define CHI_ 32
#define S_   4
#define BT_  (B_ * L_)          // 4096 rows
#define NC_  2560               // fused GEMM width: 1024 AbarI | 1024 G | 512 gate
#define SLOTF 1088              // floats per scan LDS slot (4096B row + 256B c dup)
#define SLOTB 4352              // bytes per slot

// ---------------------------------------------------------------------------
// Cross-lane helpers (all VALU-pipe)
// ---------------------------------------------------------------------------
__device__ __forceinline__ float readlane_f(float v, int l) {
    return __int_as_float(__builtin_amdgcn_readlane(__float_as_int(v), l));
}

template <int CTRL>
__device__ __forceinline__ float dpp_add(float x) {
    int y = __builtin_amdgcn_update_dpp(0, __float_as_int(x), CTRL, 0xf, 0xf, true);
    return x + __int_as_float(y);
}

// Sum of lanes 0..31, valid in lane 31 (row_shr moves toward HIGHER lanes).
__device__ __forceinline__ float reduce32_to_lane31(float x) {
    x = dpp_add<0x111>(x);
    x = dpp_add<0x112>(x);
    x = dpp_add<0x114>(x);
    x = dpp_add<0x118>(x);
    x = dpp_add<0x142>(x);  // row_bcast15 -> lane31
    return x;
}

// ---------------------------------------------------------------------------
// Async global->LDS DMA (HW: wave-uniform LDS base + lane*size).
// ---------------------------------------------------------------------------
__device__ __forceinline__ void dma16(const float* g, float* l) {
    __builtin_amdgcn_global_load_lds(
        (const __attribute__((address_space(1))) float*)g,
        (__attribute__((address_space(3))) float*)l, 16, 0, 0);
}
__device__ __forceinline__ void dma4(const float* g, float* l) {
    __builtin_amdgcn_global_load_lds(
        (const __attribute__((address_space(1))) float*)g,
        (__attribute__((address_space(3))) float*)l, 4, 0, 0);
}

__device__ __forceinline__ unsigned lds_off(const void* p) {
    return (unsigned)(unsigned long long)
        (const __attribute__((address_space(3))) void*)p;
}

// ---------------------------------------------------------------------------
// Scan stage blobs. Layout inside a slot (floats): [0..1024) row with
// LDS[128e + 4r + l'] = Abar[4e+l'][r]; [1024..1088) c duplicated x2.
// Main blob: gate slot DMA (vmcnt(30)), issue 9 reads for the NEXT iter,
// drain the PREVIOUS blob's 9 reads (lgkmcnt(9) leaves own 9 in flight),
// emit a zero token that gates all consumers of the previous reads.
// No tied operands (R6), no "memory" clobber (keeps compiler waitcnt out).
// ---------------------------------------------------------------------------
__device__ __forceinline__ void stage_blob(
    float4& o0, float4& o1, float4& o2, float4& o3,
    float4& o4, float4& o5, float4& o6, float4& o7,
    float& oc, float& z, unsigned ra, unsigned rc)
{
    asm volatile(
        "s_waitcnt vmcnt(30)\n\t"
        "ds_read_b128 %0, %10 offset:0\n\t"
        "ds_read_b128 %1, %10 offset:512\n\t"
        "ds_read_b128 %2, %10 offset:1024\n\t"
        "ds_read_b128 %3, %10 offset:1536\n\t"
        "ds_read_b128 %4, %10 offset:2048\n\t"
        "ds_read_b128 %5, %10 offset:2560\n\t"
        "ds_read_b128 %6, %10 offset:3072\n\t"
        "ds_read_b128 %7, %10 offset:3584\n\t"
        "ds_read_b32  %8, %11 offset:4096\n\t"
        "s_waitcnt lgkmcnt(9)\n\t"
        "v_mov_b32 %9, 0"
        : "=&v"(o0), "=&v"(o1), "=&v"(o2), "=&v"(o3),
          "=&v"(o4), "=&v"(o5), "=&v"(o6), "=&v"(o7),
          "=&v"(oc), "=&v"(z)
        : "v"(ra), "v"(rc));
}

// Prologue stage: gate row-0 DMA (40 outstanding, 35 newer), read slot 0.
__device__ __forceinline__ void stage_blob_pro(
    float4& o0, float4& o1, float4& o2, float4& o3,
    float4& o4, float4& o5, float4& o6, float4& o7,
    float& oc, unsigned ra, unsigned rc)
{
    asm volatile(
        "s_waitcnt vmcnt(35)\n\t"
        "ds_read_b128 %0, %9 offset:0\n\t"
        "ds_read_b128 %1, %9 offset:512\n\t"
        "ds_read_b128 %2, %9 offset:1024\n\t"
        "ds_read_b128 %3, %9 offset:1536\n\t"
        "ds_read_b128 %4, %9 offset:2048\n\t"
        "ds_read_b128 %5, %9 offset:2560\n\t"
        "ds_read_b128 %6, %9 offset:3072\n\t"
        "ds_read_b128 %7, %9 offset:3584\n\t"
        "ds_read_b32  %8, %10 offset:4096"
        : "=&v"(o0), "=&v"(o1), "=&v"(o2), "=&v"(o3),
          "=&v"(o4), "=&v"(o5), "=&v"(o6), "=&v"(o7),
          "=&v"(oc)
        : "v"(ra), "v"(rc));
}

// ---------------------------------------------------------------------------
// buildW: fold W_site with (sum_p) into Abar columns in the scan layout
// f = 128*(l>>2) + 4r + (l&3); fold with W_bridge -> G; append W_gate.
// Block 512 = bias block (same folds on b_site / b_gate).
// ---------------------------------------------------------------------------
__global__ __launch_bounds__(256) void buildW_kernel(
    const float* __restrict__ Ws, const float* __restrict__ bs,
    const float* __restrict__ Wb, const float* __restrict__ Wg,
    const float* __restrict__ bg, float* __restrict__ Wcomb,
    float* __restrict__ biasC)
{
    const int tid = threadIdx.x;

    if (blockIdx.x == 512) {   // bias block
        for (int f = tid; f < NC_; f += 256) {
            float acc;
            if (f < 1024) {
                const int e = f >> 7, rem = f & 127;
                const int r = rem >> 2, lp = rem & 3;
                const int l = 4 * e + lp;
                const float* p = bs + l * 128 + r;
                acc = p[0] + p[32] + p[64] + p[96];
            } else if (f < 2048) {
                const int g = f - 1024, l = g >> 5, j = g & 31;
                acc = 0.f;
                for (int pr = 0; pr < 128; ++pr)
                    acc = fmaf(bs[l * 128 + pr], Wb[pr * 32 + j], acc);
            } else {
                acc = bg[f - 2048];
            }
            biasC[f] = acc;
        }
        return;
    }

    __shared__ float wsrow[4096];
    __shared__ float wbs[4096];

    const int d = blockIdx.x;
    #pragma unroll
    for (int i = 0; i < 16; ++i) {
        wsrow[i * 256 + tid] = Ws[(size_t)d * 4096 + i * 256 + tid];
        wbs[i * 256 + tid]   = Wb[i * 256 + tid];
    }
    __syncthreads();

    float* wrow = Wcomb + (size_t)d * NC_;

    // Abar columns in scan layout
    #pragma unroll
    for (int ii = 0; ii < 4; ++ii) {
        const int f = ii * 256 + tid;
        const int e = f >> 7, rem = f & 127;
        const int r = rem >> 2, lp = rem & 3;
        const int l = 4 * e + lp;
        const float* p = wsrow + l * 128 + r;
        wrow[f] = p[0] + p[32] + p[64] + p[96];
    }
    // G = Ws-row folded with W_bridge
    #pragma unroll
    for (int ii = 0; ii < 4; ++ii) {
        const int g = ii * 256 + tid;
        const int l = g >> 5, j = g & 31;
        float acc = 0.f;
        #pragma unroll 8
        for (int pr = 0; pr < 128; ++pr)
            acc = fmaf(wsrow[l * 128 + pr], wbs[pr * 32 + j], acc);
        wrow[1024 + g] = acc;
    }
    // gate copy
    #pragma unroll
    for (int ii = 0; ii < 2; ++ii) {
        const int c = ii * 256 + tid;
        wrow[2048 + c] = Wg[(size_t)d * 512 + c];
    }
}

// ---------------------------------------------------------------------------
// Generic fp32 GEMM with bias (unchanged R5)
// ---------------------------------------------------------------------------
__global__ __launch_bounds__(256) void gemm_bias_kernel(
    const float* __restrict__ A, const float* __restrict__ Bm,
    const float* __restrict__ bias, float* __restrict__ C,
    int M, int N, int K)
{
    __shared__ float As[32][68];
    __shared__ float Bs[32][64];

    const int tid = threadIdx.x;
    const int tx = tid & 15;
    const int ty = tid >> 4;
    const int m0 = blockIdx.y * 64;
    const int n0 = blockIdx.x * 64;

    float c[4][4] = {};

    for (int k0 = 0; k0 < K; k0 += 32) {
        {
            const int o = tid * 8;
            const int m = o >> 5;
            const int k = o & 31;
            const float* ap = A + (size_t)(m0 + m) * K + k0 + k;
            const float4 a0 = *(const float4*)ap;
            const float4 a1 = *(const float4*)(ap + 4);
            As[k + 0][m] = a0.x; As[k + 1][m] = a0.y;
            As[k + 2][m] = a0.z; As[k + 3][m] = a0.w;
            As[k + 4][m] = a1.x; As[k + 5][m] = a1.y;
            As[k + 6][m] = a1.z; As[k + 7][m] = a1.w;
        }
        {
            const int o = tid * 8;
            const int k = o >> 6;
            const int n = o & 63;
            const float* bp = Bm + (size_t)(k0 + k) * N + n0 + n;
            *(float4*)&Bs[k][n]     = *(const float4*)bp;
            *(float4*)&Bs[k][n + 4] = *(const float4*)(bp + 4);
        }
        __syncthreads();

        #pragma unroll
        for (int kk = 0; kk < 32; ++kk) {
            const float4 av = *(const float4*)&As[kk][ty * 4];
            const float4 bv = *(const float4*)&Bs[kk][tx * 4];
            const float a[4] = {av.x, av.y, av.z, av.w};
            const float b[4] = {bv.x, bv.y, bv.z, bv.w};
            #pragma unroll
            for (int i = 0; i < 4; ++i)
                #pragma unroll
                for (int j = 0; j < 4; ++j)
                    c[i][j] = fmaf(a[i], b[j], c[i][j]);
        }
        __syncthreads();
    }

    const float4 bv = *(const float4*)&bias[n0 + tx * 4];
    #pragma unroll
    for (int i = 0; i < 4; ++i) {
        float4 outv;
        outv.x = c[i][0] + bv.x;
        outv.y = c[i][1] + bv.y;
        outv.z = c[i][2] + bv.z;
        outv.w = c[i][3] + bv.w;
        *(float4*)&C[(size_t)(m0 + ty * 4 + i) * N + n0 + tx * 4] = outv;
    }
}

// ---------------------------------------------------------------------------
// cvec: c[bt][r] = sum_l u[l]*Abar[l][r] in the new layout. One wave per bt;
// lane computes the full column via uniform readlane broadcasts (no bpermute).
// ---------------------------------------------------------------------------
__global__ __launch_bounds__(256) void cvec_kernel(
    const float* __restrict__ Cc, const float* __restrict__ x,
    float* __restrict__ cBuf)
{
    const int tid   = threadIdx.x;
    const int lane  = tid & 63;
    const int laneR = lane & 31;
    const int bt    = blockIdx.x * 4 + (tid >> 6);

    const float* bp = Cc + (size_t)bt * NC_ + 4 * laneR;
    float4 A[8];
    #pragma unroll
    for (int e = 0; e < 8; ++e)
        A[e] = *(const float4*)(bp + 128 * e);

    const float u = x[(size_t)bt * D_ + laneR];

    float acc0 = 0.f, acc1 = 0.f, acc2 = 0.f, acc3 = 0.f;
    #pragma unroll
    for (int k = 0; k < 8; ++k) {
        acc0 = fmaf(readlane_f(u, 4 * k + 0), A[k].x, acc0);
        acc1 = fmaf(readlane_f(u, 4 * k + 1), A[k].y, acc1);
        acc2 = fmaf(readlane_f(u, 4 * k + 2), A[k].z, acc2);
        acc3 = fmaf(readlane_f(u, 4 * k + 3), A[k].w, acc3);
    }
    const float c = (acc0 + acc1) + (acc2 + acc3);
    if (lane < 32) cBuf[(size_t)bt * 32 + lane] = c;
}

// ---------------------------------------------------------------------------
// Serial scan. One wave per batch. Lane i computes the FULL column dot
// m[i&31] = sum_l w[l]*A[l][i&31]: broadcasts via 32 uniform v_readlane
// (VALU), 4 independent fma chains of 8 -> m already in standard layout.
// Zero cross-lane LDS ops on the recurrence path. Two-level pipeline:
//   L1: global->LDS DMA ring, 8 slots ahead (vmcnt(30) gate)
//   L2: LDS->VGPR ds_read, 1 iter ahead (ping-pong A/B register sets,
//       lgkmcnt(9) drain in the next blob; token gates consumers)
// Per iter: 1 w-store + 5 DMA = 6 vm ops; newer-than-row-(n+1) >= 30 always.
// ---------------------------------------------------------------------------
__global__ __launch_bounds__(64, 1) void scan_kernel(
    const float* __restrict__ Cc, const float* __restrict__ cBuf,
    float* __restrict__ wOut)
{
    __shared__ __align__(16) float slots[8][SLOTF];

    const int b   = blockIdx.x;
    const int tid = threadIdx.x;
    const int laneR = tid & 31;

    const float* Crow = Cc + (size_t)b * L_ * NC_;
    const float* cb   = cBuf + (size_t)b * L_ * 32;
    float*       wo   = wOut + (size_t)b * L_ * 64 + tid;

    const unsigned base   = lds_off(&slots[0][0]);
    const unsigned raBase = base + 16u * (unsigned)laneR;  // row vaddr (b128)
    const unsigned rcBase = base + 4u * (unsigned)laneR;   // c vaddr (+4096 imm)

    // ---- prologue: DMA rows 0..7 (40 vm ops, no stores) ----
    #pragma unroll
    for (int k = 0; k < 8; ++k) {
        const float* rp = Crow + (size_t)k * NC_;
        #pragma unroll
        for (int q = 0; q < 4; ++q)
            dma16(rp + 256 * q + 4 * tid, &slots[k][256 * q]);
        dma4(cb + k * 32 + laneR, &slots[k][1024]);
    }

    // ---- stage slot 0 -> set A ----
    float4 A0, A1, A2, A3, A4, A5, A6, A7;
    float4 B0, B1, B2, B3, B4, B5, B6, B7;
    float  cA, cB, z;
    stage_blob_pro(A0, A1, A2, A3, A4, A5, A6, A7, cA, raBase, rcBase);

    float w = 0.f;   // w_0 = 0 (h_0 = 0)

    for (int t = 0; t < L_; t += 8) {
        #pragma unroll
        for (int j = 0; j < 8; ++j) {
            const int n = t + j;
            const int sn = (j + 1) & 7;
            const unsigned ra = raBase + (unsigned)(sn * SLOTB);
            const unsigned rc = rcBase + (unsigned)(sn * SLOTB);

            // blob: gate row n+1 DMA; read slot sn -> other set; drain prev
            if ((j & 1) == 0)
                stage_blob(B0, B1, B2, B3, B4, B5, B6, B7, cB, z, ra, rc);
            else
                stage_blob(A0, A1, A2, A3, A4, A5, A6, A7, cA, z, ra, rc);

            // store w_n (1 vm op)
            wo[n * 64] = w;

            // DMA row n+8 -> slot j (5 vm ops; slot's reads drained above)
            {
                int rowN = n + 8; if (rowN > L_ - 1) rowN = L_ - 1;
                const float* rp = Crow + (size_t)rowN * NC_;
                #pragma unroll
                for (int q = 0; q < 4; ++q)
                    dma16(rp + 256 * q + 4 * tid, &slots[j][256 * q]);
                dma4(cb + rowN * 32 + laneR, &slots[j][1024]);
            }

            // ---- norm (VALU, parallel) ----
            float red = reduce32_to_lane31(w * w);
            const float n2 = readlane_f(red, 31);
            const float rinv = rsqrtf(n2 + 1e-24f);

            // ---- matvec: 4 chains of 8, init = token z (orders after blob)
            float acc0 = z, acc1 = z, acc2 = z, acc3 = z;
            if ((j & 1) == 0) {
                #define CH(k, Ak)                                            \
                    acc0 = fmaf(readlane_f(w, 4*k + 0), Ak.x, acc0);         \
                    acc1 = fmaf(readlane_f(w, 4*k + 1), Ak.y, acc1);         \
                    acc2 = fmaf(readlane_f(w, 4*k + 2), Ak.z, acc2);         \
                    acc3 = fmaf(readlane_f(w, 4*k + 3), Ak.w, acc3);
                CH(0, A0) CH(1, A1) CH(2, A2) CH(3, A3)
                CH(4, A4) CH(5, A5) CH(6, A6) CH(7, A7)
                const float m = (acc0 + acc1) + (acc2 + acc3);
                w = fmaf(m, rinv, cA);
            } else {
                CH(0, B0) CH(1, B1) CH(2, B2) CH(3, B3)
                CH(4, B4) CH(5, B5) CH(6, B6) CH(7, B7)
                #undef CH
                const float m = (acc0 + acc1) + (acc2 + acc3);
                w = fmaf(m, rinv, cB);
            }
        }
    }
}

// ---------------------------------------------------------------------------
// Fused tail: left = w/||w|| + u; y1 = left.G + bb; out-proj; LN; gated res.
// ---------------------------------------------------------------------------
__global__ __launch_bounds__(256) void tail_kernel(
    const float* __restrict__ Cc, const float* __restrict__ x,
    const float* __restrict__ wBuf, const float* __restrict__ bb,
    const float* __restrict__ Wout, const float* __restrict__ bout,
    const float* __restrict__ gamma, const float* __restrict__ beta,
    float* __restrict__ out)
{
    __shared__ float lf[32];
    __shared__ float part[4][32];
    __shared__ float ys[32];
    __shared__ float red1[4], red2[4];

    const int bt = blockIdx.x;
    const int tid = threadIdx.x;

    if (tid < 64) {
        const float wv = wBuf[(size_t)bt * 64 + tid];
        float red = reduce32_to_lane31(wv * wv);
        const float n2 = readlane_f(red, 31);
        const float rn = rsqrtf(n2 + 1e-24f);
        if (tid < 32)
            lf[tid] = fmaf(wv, rn, x[(size_t)bt * D_ + tid]);  // left = h + u
    }
    __syncthreads();

    if (tid < 128) {
        const int j = tid & 31, q = tid >> 5;
        const float* Gp = Cc + (size_t)bt * NC_ + 1024;
        float p = 0.f;
        #pragma unroll
        for (int i = 0; i < 8; ++i)
            p = fmaf(lf[8 * q + i], Gp[(8 * q + i) * 32 + j], p);
        part[q][j] = p;
    }
    __syncthreads();
    if (tid < 32)
        ys[tid] = part[0][tid] + part[1][tid] + part[2][tid] + part[3][tid]
                + bb[tid];
    __syncthreads();

    float yv[2];
    #pragma unroll
    for (int q = 0; q < 2; ++q) {
        const int d = tid + q * 256;
        float acc = bout[d];
        #pragma unroll
        for (int j = 0; j < 32; ++j)
            acc = fmaf(ys[j], Wout[j * D_ + d], acc);
        yv[q] = acc;
    }

    float s1 = yv[0] + yv[1];
    float s2 = yv[0] * yv[0] + yv[1] * yv[1];
    #pragma unroll
    for (int m = 1; m <= 32; m <<= 1) {
        s1 += __shfl_xor(s1, m);
        s2 += __shfl_xor(s2, m);
    }
    const int wid = tid >> 6;
    if ((tid & 63) == 0) { red1[wid] = s1; red2[wid] = s2; }
    __syncthreads();
    const float S1 = red1[0] + red1[1] + red1[2] + red1[3];
    const float S2 = red2[0] + red2[1] + red2[2] + red2[3];
    const float mu  = S1 * (1.f / (float)D_);
    const float var = S2 * (1.f / (float)D_) - mu * mu;
    const float rstd = rsqrtf(var + 1e-6f);

    #pragma unroll
    for (int q = 0; q < 2; ++q) {
        const int d = tid + q * 256;
        const size_t gi = (size_t)bt * D_ + d;
        const float yn = (yv[q] - mu) * rstd * gamma[d] + beta[d];
        const float zg = Cc[(size_t)bt * NC_ + 2048 + d];
        const float g = 1.f / (1.f + expf(-zg));
        const float xv = x[gi];
        out[gi] = g * yn + (1.f - g) * xv;
    }
}

// ---------------------------------------------------------------------------
extern "C" void kernel_launch(void* const* d_in, const int* in_sizes, int n_in,
                              void* d_out, int out_size, void* d_ws, size_t ws_size,
                              hipStream_t stream)
{
    const float* x        = (const float*)d_in[0];
    const float* W_site   = (const float*)d_in[1];
    const float* b_site   = (const float*)d_in[2];
    const float* W_bridge = (const float*)d_in[3];
    const float* b_bridge = (const float*)d_in[4];
    const float* W_out    = (const float*)d_in[5];
    const float* b_out    = (const float*)d_in[6];
    const float* gamma    = (const float*)d_in[7];
    const float* beta     = (const float*)d_in[8];
    const float* W_gate   = (const float*)d_in[9];
    const float* b_gate   = (const float*)d_in[10];
    float* out = (float*)d_out;

    float* ws = (float*)d_ws;
    float* Wcomb = ws;                            //   512*2560
    float* biasC = Wcomb + (size_t)512 * NC_;
    float* Cc    = biasC + NC_;                   // 4096*2560 (42 MB)
    float* cBuf  = Cc    + (size_t)BT_ * NC_;
    float* wBuf  = cBuf  + (size_t)BT_ * 32;

    // 0. fold weights: [Abar-layout | G | W_gate] + fused bias
    buildW_kernel<<<dim3(513), dim3(256), 0, stream>>>(
        W_site, b_site, W_bridge, W_gate, b_gate, Wcomb, biasC);

    // 1. one fused GEMM: C = x @ Wcomb + biasC   [4096 x 2560, K=512]
    gemm_bias_kernel<<<dim3(NC_ / 64, BT_ / 64), dim3(256), 0, stream>>>(
        x, Wcomb, biasC, Cc, BT_, NC_, D_);

    // 2. c vectors: c = u . Abar  (fully parallel)
    cvec_kernel<<<dim3(BT_ / 4), dim3(256), 0, stream>>>(Cc, x, cBuf);

    // 3. serial scan (4 waves total) -> w_t
    scan_kernel<<<dim3(B_), dim3(64), 0, stream>>>(Cc, cBuf, wBuf);

    // 4. fused tail: bridge + out-proj + LN + gated residual
    tail_kernel<<<dim3(BT_), dim3(256), 0, stream>>>(
        Cc, x, wBuf, b_bridge, W_out, b_out, gamma, beta, out);
}